// Round 4
// baseline (302.449 us; speedup 1.0000x reference)
//
#include <hip/hip_runtime.h>
#include <stdint.h>
#include <stddef.h>

#define NB 4
#define NC 256
#define NSP 4096
#define NG 32
#define CPG 8
#define GEPS 1e-5f
#define SCALE 0.0625f  // d^-0.5, d=256
#define NROWS (NB * NSP)  // 16384 global q-rows
#define JSPLIT 4

typedef __attribute__((ext_vector_type(8))) short s8v;
typedef __attribute__((ext_vector_type(4))) float f4v;
typedef __attribute__((ext_vector_type(16))) float f16v;
typedef __attribute__((ext_vector_type(4))) unsigned short us4v;
typedef __attribute__((ext_vector_type(4))) unsigned int u4v;

__device__ __forceinline__ float b2f(unsigned short h) {
  union { unsigned u; float f; } x; x.u = ((unsigned)h) << 16; return x.f;
}
__device__ __forceinline__ unsigned short f2b(float f) {
  union { float f; unsigned u; } x; x.f = f;
  unsigned r = x.u + 0x7fffu + ((x.u >> 16) & 1u);
  return (unsigned short)(r >> 16);
}
// pack two f32 -> one u32 of 2 bf16 (RTZ), lo in low half
__device__ __forceinline__ unsigned packbf(float lo, float hi) {
  union { float f; unsigned u; } a, b; a.f = lo; b.f = hi;
  return (b.u & 0xffff0000u) | (a.u >> 16);
}

// ---- fp32 -> bf16 convert, both weight blobs in one launch ----
__global__ __launch_bounds__(256) void cvt2_kernel(
    const float* __restrict__ qw, const float* __restrict__ pw,
    unsigned short* __restrict__ wq, unsigned short* __restrict__ wp) {
  int i = (blockIdx.x * 256 + threadIdx.x) * 4;
  const float* src; unsigned short* dst; int j;
  if (i < 3 * NC * NC) { src = qw; dst = wq; j = i; }
  else { src = pw; dst = wp; j = i - 3 * NC * NC; }
  float4 v = *(const float4*)(src + j);
  us4v p;
  p[0] = f2b(v.x); p[1] = f2b(v.y); p[2] = f2b(v.z); p[3] = f2b(v.w);
  *(us4v*)(dst + j) = p;
}

// -------------------- GroupNorm: x fp32 (B,C,N) -> xn bf16 (B,N,C) --------------------
__global__ __launch_bounds__(256) void gn_kernel(
    const float* __restrict__ x, const float* __restrict__ w,
    const float* __restrict__ bias, unsigned short* __restrict__ xn) {
  int b = blockIdx.x >> 5;
  int g = blockIdx.x & 31;
  const float* xp = x + ((size_t)b * NC + (size_t)g * CPG) * NSP;
  int t = threadIdx.x;
  float s = 0.f, ss = 0.f;
  for (int i = 4 * t; i < CPG * NSP; i += 1024) {
    float4 v = *(const float4*)(xp + i);
    s += v.x + v.y + v.z + v.w;
    ss += v.x * v.x + v.y * v.y + v.z * v.z + v.w * v.w;
  }
  __shared__ float r1[256], r2[256];
  r1[t] = s; r2[t] = ss;
  __syncthreads();
  for (int off = 128; off > 0; off >>= 1) {
    if (t < off) { r1[t] += r1[t + off]; r2[t] += r2[t + off]; }
    __syncthreads();
  }
  float mean = r1[0] * (1.f / (CPG * NSP));
  float var  = r2[0] * (1.f / (CPG * NSP)) - mean * mean;
  float rstd = rsqrtf(var + GEPS);
  float wv[CPG], bv[CPG];
  for (int c = 0; c < CPG; c++) {
    wv[c] = w[g * CPG + c] * rstd;
    bv[c] = bias[g * CPG + c] - mean * wv[c];
  }
  for (int n = t; n < NSP; n += 256) {
    s8v pk;
    for (int c = 0; c < CPG; c++) {
      float v = xp[(size_t)c * NSP + n];
      ((unsigned short*)&pk)[c] = f2b(v * wv[c] + bv[c]);
    }
    *(s8v*)(xn + ((size_t)(b * NSP + n) * NC + g * CPG)) = pk;
  }
}

// ---- Fused QKV GEMM: one launch, grid (NSP/128, 6, NB). sec = y>>1 (0=q,1=k,2=v). ----
// Swizzles for 32x32x16 flash:
//  Q/K (sec<2): per 32-token tile (8192 shorts), element (tok, d) at
//    (d>>4)*512 + ((d>>3)&1)*256 + (tok&31)*8 + (d&7)   [A/B-frag linear, lane=hi*32+tok]
//  V  (sec=2): per 32-token tile, element (tok, d) at
//    (d>>5)*1024 + ((tok>>4)&1)*512 + ((tok>>3)&1)*256 + (d&31)*8 + (tok&7)  [V^T A-frag]
__global__ __launch_bounds__(256) void qkv_gemm(
    const unsigned short* __restrict__ W, const unsigned short* __restrict__ xnG,
    const float* __restrict__ qkvb,
    unsigned short* __restrict__ q, unsigned short* __restrict__ k,
    unsigned short* __restrict__ v) {
  const int sec = blockIdx.y >> 1;
  const int m0 = (blockIdx.y & 1) * 128;
  const int n0 = blockIdx.x * 128;
  const unsigned short* A  = W + (size_t)sec * NC * NC;
  const unsigned short* Bt = xnG + (size_t)blockIdx.z * NSP * NC;
  unsigned short* dst = (sec == 0 ? q : (sec == 1 ? k : v)) + (size_t)blockIdx.z * NSP * NC;
  const float scl = (sec == 0) ? SCALE : 1.f;

  __shared__ unsigned short As[128 * 32], Bs[128 * 32];
  const int t = threadIdx.x;
  const int lane = t & 63, wave = t >> 6;
  const int wm = (wave >> 1) * 64, wn = (wave & 1) * 64;
  const int l16 = lane & 15, quad = lane >> 4;
  const int srow = t >> 2, skc = (t & 3) * 8;

  f4v acc[4][4];
  for (int mi = 0; mi < 4; mi++)
    for (int ni = 0; ni < 4; ni++)
      acc[mi][ni] = (f4v){0.f, 0.f, 0.f, 0.f};

  const unsigned short* Ag0 = A  + (size_t)(m0 + srow) * NC + skc;
  const unsigned short* Ag1 = A  + (size_t)(m0 + srow + 64) * NC + skc;
  const unsigned short* Bg0 = Bt + (size_t)(n0 + srow) * NC + skc;
  const unsigned short* Bg1 = Bt + (size_t)(n0 + srow + 64) * NC + skc;

  for (int k0 = 0; k0 < NC; k0 += 32) {
    s8v a0 = *(const s8v*)(Ag0 + k0);
    s8v a1 = *(const s8v*)(Ag1 + k0);
    s8v b0 = *(const s8v*)(Bg0 + k0);
    s8v b1 = *(const s8v*)(Bg1 + k0);
    __syncthreads();
    *(s8v*)(As + srow * 32 + skc) = a0;
    *(s8v*)(As + (srow + 64) * 32 + skc) = a1;
    *(s8v*)(Bs + srow * 32 + skc) = b0;
    *(s8v*)(Bs + (srow + 64) * 32 + skc) = b1;
    __syncthreads();
    s8v af[4], bfr[4];
    for (int mi = 0; mi < 4; mi++)
      af[mi] = *(const s8v*)(As + (wm + mi * 16 + l16) * 32 + quad * 8);
    for (int ni = 0; ni < 4; ni++)
      bfr[ni] = *(const s8v*)(Bs + (wn + ni * 16 + l16) * 32 + quad * 8);
    for (int mi = 0; mi < 4; mi++)
      for (int ni = 0; ni < 4; ni++)
        acc[mi][ni] = __builtin_amdgcn_mfma_f32_16x16x32_bf16(af[mi], bfr[ni], acc[mi][ni], 0, 0, 0);
  }

  for (int mi = 0; mi < 4; mi++) {
    const int rb = m0 + wm + mi * 16 + quad * 4;   // d within section (0..255)
    for (int ni = 0; ni < 4; ni++) {
      const int col = n0 + wn + ni * 16 + l16;     // token
      f4v a = acc[mi][ni];
      if (sec < 2) {  // Q/K frag tile: rb&7 in {0,4}, octet-constant -> 8B store
        us4v pk;
        for (int r = 0; r < 4; r++)
          pk[r] = f2b((a[r] + qkvb[sec * NC + rb + r]) * scl);
        const size_t off = (size_t)(col >> 5) * 8192 + (rb >> 4) * 512 +
                           ((rb >> 3) & 1) * 256 + (col & 31) * 8 + (rb & 7);
        *(us4v*)(dst + off) = pk;
      } else {        // V^T frag tile: d varies per r -> scalar stores
        for (int r = 0; r < 4; r++) {
          const int d = rb + r;
          const size_t off = (size_t)(col >> 5) * 8192 + (d >> 5) * 1024 +
                             ((col >> 4) & 1) * 512 + ((col >> 3) & 1) * 256 +
                             (d & 31) * 8 + (col & 7);
          dst[off] = f2b(a[r] + qkvb[2 * NC + d]);
        }
      }
    }
  }
}

// ---- Flash v9: v6 structure, K/V read DIRECTLY from global (no LDS, no barriers) ----
// grid (NSP/128, NB, JSPLIT), 256 thr, 2 blocks/CU, 2 waves/SIMD.
// K/V are frag-linear in global: a wave's frag read = coalesced 1KB global load,
// served from L1/L2 (32KB tile shared by 8 waves/CU). Deletes the entire LDS pipe
// (reads + staged writes + dbuf + __syncthreads) that was ~70% busy in v6.
__global__ __launch_bounds__(256, 2) void flash9_kernel(
    const unsigned short* __restrict__ q, const unsigned short* __restrict__ k,
    const unsigned short* __restrict__ v, unsigned short* __restrict__ Opart,
    float* __restrict__ Lpart) {
  const int qt = blockIdx.x, b = blockIdx.y, js = blockIdx.z;
  const size_t sNC = (size_t)NSP * NC;
  const unsigned short* qb = q + b * sNC;
  const unsigned short* kb = k + b * sNC;
  const unsigned short* vb = v + b * sNC;
  const int t = threadIdx.x, lane = t & 63, w = t >> 6;

  f16v zero16;
  #pragma unroll
  for (int r = 0; r < 16; r++) zero16[r] = 0.f;

  // Q resident as B-frags: wave w owns 32-token tile qt*4 + w
  s8v qf[16];
  {
    const unsigned short* qp = qb + (size_t)(qt * 4 + w) * 8192 + lane * 8;
    #pragma unroll
    for (int kc = 0; kc < 16; kc++)
      qf[kc] = *(const s8v*)(qp + kc * 512);
  }

  f16v accO[8];
  #pragma unroll
  for (int dt = 0; dt < 8; dt++) accO[dt] = zero16;
  float l4[4] = {0.f, 0.f, 0.f, 0.f};

  const int tbeg = (js * (NSP / JSPLIT)) >> 5;   // first 32-j frag tile
  const int tcnt = (NSP / JSPLIT) >> 5;          // 32 tiles

  for (int tt = tbeg; tt < tbeg + tcnt; tt++) {
    const unsigned short* Kt = kb + (size_t)tt * 8192 + lane * 8;
    const unsigned short* Vt = vb + (size_t)tt * 8192 + lane * 8;

    // S^T = K . Q^T over d = 256 (16 k-steps); 16 independent global loads
    // hoist ahead of the MFMA chain (compiler inserts counted vmcnt waits).
    f16v accS = zero16;
    #pragma unroll
    for (int kc = 0; kc < 16; kc++) {
      s8v kf = *(const s8v*)(Kt + kc * 512);
      accS = __builtin_amdgcn_mfma_f32_32x32x16_bf16(kf, qf[kc], accS, 0, 0, 0);
    }

    // p = exp(s): q pre-scaled, no max (80-sigma headroom); l lane-local (col=q)
    float p[16];
    #pragma unroll
    for (int r = 0; r < 16; r++) {
      p[r] = __expf(accS[r]);
      l4[r & 3] += p[r];
    }

    // Repack P rows (j) into PV B-frags (T12: packbf + permlane32_swap)
    u4v pw0, pw1;
    {
      unsigned a0 = packbf(p[0], p[1]),   b0 = packbf(p[4], p[5]);
      asm("v_permlane32_swap_b32 %0, %1" : "+v"(a0), "+v"(b0));
      unsigned a1 = packbf(p[2], p[3]),   b1 = packbf(p[6], p[7]);
      asm("v_permlane32_swap_b32 %0, %1" : "+v"(a1), "+v"(b1));
      unsigned a2 = packbf(p[8], p[9]),   b2 = packbf(p[12], p[13]);
      asm("v_permlane32_swap_b32 %0, %1" : "+v"(a2), "+v"(b2));
      unsigned a3 = packbf(p[10], p[11]), b3 = packbf(p[14], p[15]);
      asm("v_permlane32_swap_b32 %0, %1" : "+v"(a3), "+v"(b3));
      pw0[0] = a0; pw0[1] = a1; pw0[2] = b0; pw0[3] = b1;  // j-half 0 (j=0..15)
      pw1[0] = a2; pw1[1] = a3; pw1[2] = b2; pw1[3] = b3;  // j-half 1 (j=16..31)
    }
    const s8v pb0 = __builtin_bit_cast(s8v, pw0);
    const s8v pb1 = __builtin_bit_cast(s8v, pw1);

    // out^T += V^T . P^T : 16 independent global V-frag loads + 16 MFMA
    #pragma unroll
    for (int dt = 0; dt < 8; dt++) {
      s8v vf0 = *(const s8v*)(Vt + dt * 1024);
      s8v vf1 = *(const s8v*)(Vt + dt * 1024 + 512);
      accO[dt] = __builtin_amdgcn_mfma_f32_32x32x16_bf16(vf0, pb0, accO[dt], 0, 0, 0);
      accO[dt] = __builtin_amdgcn_mfma_f32_32x32x16_bf16(vf1, pb1, accO[dt], 0, 0, 0);
    }
  }

  // epilogue: lane owns q = lane&31; combine lane halves, write L + O^T
  float l_acc = l4[0] + l4[1] + l4[2] + l4[3];
  const float ltot = l_acc + __shfl_xor(l_acc, 32, 64);
  const int qrow = b * NSP + qt * 128 + w * 32 + (lane & 31);
  if (lane < 32)
    Lpart[(size_t)js * NROWS + qrow] = ltot;

  unsigned short* Op = Opart + ((size_t)js * NROWS + qrow) * NC;
  const int hi = lane >> 5;
  #pragma unroll
  for (int dt = 0; dt < 8; dt++) {
    #pragma unroll
    for (int g = 0; g < 4; g++) {
      us4v pk;
      #pragma unroll
      for (int r = 0; r < 4; r++)
        pk[r] = f2b(accO[dt][g * 4 + r]);
      // d = dt*32 + g*8 + hi*4 + r
      *(us4v*)(Op + dt * 32 + g * 8 + hi * 4) = pk;
    }
  }
}

// ---- Fused proj GEMM with inline merge of JSPLIT partials ----
__global__ __launch_bounds__(256) void proj_gemm(
    const unsigned short* __restrict__ Wp, const unsigned short* __restrict__ Opart,
    const float* __restrict__ Lpart, const float* __restrict__ pb,
    const float* __restrict__ x, float* __restrict__ out) {
  const int z = blockIdx.z, m0 = blockIdx.y * 128, n0 = blockIdx.x * 128;
  __shared__ unsigned short As[128 * 32], Bs[128 * 32];
  const int t = threadIdx.x;
  const int lane = t & 63, wave = t >> 6;
  const int wm = (wave >> 1) * 64, wn = (wave & 1) * 64;
  const int l16 = lane & 15, quad = lane >> 4;
  const int srow = t >> 2, skc = (t & 3) * 8;

  const int prow0 = z * NSP + n0 + srow;
  const int prow1 = prow0 + 64;
  float ls0 = 0.f, ls1 = 0.f;
  for (int js = 0; js < JSPLIT; js++) {
    ls0 += Lpart[(size_t)js * NROWS + prow0];
    ls1 += Lpart[(size_t)js * NROWS + prow1];
  }
  const float inv0 = 1.f / ls0, inv1 = 1.f / ls1;

  f4v acc[4][4];
  for (int mi = 0; mi < 4; mi++)
    for (int ni = 0; ni < 4; ni++)
      acc[mi][ni] = (f4v){0.f, 0.f, 0.f, 0.f};

  const unsigned short* Ag0 = Wp + (size_t)(m0 + srow) * NC + skc;
  const unsigned short* Ag1 = Wp + (size_t)(m0 + srow + 64) * NC + skc;

  for (int k0 = 0; k0 < NC; k0 += 32) {
    s8v a0 = *(const s8v*)(Ag0 + k0);
    s8v a1 = *(const s8v*)(Ag1 + k0);
    float bv0[8], bv1[8];
    for (int e = 0; e < 8; e++) { bv0[e] = 0.f; bv1[e] = 0.f; }
    for (int js = 0; js < JSPLIT; js++) {
      const s8v o0 = *(const s8v*)(Opart + ((size_t)js * NROWS + prow0) * NC + k0 + skc);
      const s8v o1 = *(const s8v*)(Opart + ((size_t)js * NROWS + prow1) * NC + k0 + skc);
      for (int e = 0; e < 8; e++) {
        bv0[e] += b2f(((const unsigned short*)&o0)[e]);
        bv1[e] += b2f(((const unsigned short*)&o1)[e]);
      }
    }
    s8v b0, b1;
    for (int e = 0; e < 8; e++) {
      ((unsigned short*)&b0)[e] = f2b(bv0[e] * inv0);
      ((unsigned short*)&b1)[e] = f2b(bv1[e] * inv1);
    }
    __syncthreads();
    *(s8v*)(As + srow * 32 + skc) = a0;
    *(s8v*)(As + (srow + 64) * 32 + skc) = a1;
    *(s8v*)(Bs + srow * 32 + skc) = b0;
    *(s8v*)(Bs + (srow + 64) * 32 + skc) = b1;
    __syncthreads();
    s8v af[4], bfr[4];
    for (int mi = 0; mi < 4; mi++)
      af[mi] = *(const s8v*)(As + (wm + mi * 16 + l16) * 32 + quad * 8);
    for (int ni = 0; ni < 4; ni++)
      bfr[ni] = *(const s8v*)(Bs + (wn + ni * 16 + l16) * 32 + quad * 8);
    for (int mi = 0; mi < 4; mi++)
      for (int ni = 0; ni < 4; ni++)
        acc[mi][ni] = __builtin_amdgcn_mfma_f32_16x16x32_bf16(af[mi], bfr[ni], acc[mi][ni], 0, 0, 0);
  }

  float* C = out + (size_t)z * NC * NSP;
  const float* R = x + (size_t)z * NC * NSP;
  for (int mi = 0; mi < 4; mi++) {
    const int rb = m0 + wm + mi * 16 + quad * 4;
    for (int ni = 0; ni < 4; ni++) {
      const int col = n0 + wn + ni * 16 + l16;
      f4v a = acc[mi][ni];
      for (int r = 0; r < 4; r++)
        C[(size_t)(rb + r) * NSP + col] =
            a[r] + pb[rb + r] + R[(size_t)(rb + r) * NSP + col];
    }
  }
}

extern "C" void kernel_launch(void* const* d_in, const int* in_sizes, int n_in,
                              void* d_out, int out_size, void* d_ws, size_t ws_size,
                              hipStream_t stream) {
  const float* x      = (const float*)d_in[0];
  const float* norm_w = (const float*)d_in[1];
  const float* norm_b = (const float*)d_in[2];
  const float* qkv_w  = (const float*)d_in[3];
  const float* qkv_b  = (const float*)d_in[4];
  const float* proj_w = (const float*)d_in[5];
  const float* proj_b = (const float*)d_in[6];
  float* out = (float*)d_out;  // fp32 output

  char* ws = (char*)d_ws;
  unsigned short* wq = (unsigned short*)ws;                     // 384 KB
  unsigned short* wp = (unsigned short*)(ws + 3 * NC * NC * 2); // 128 KB
  char* wst = ws + (1 << 20);
  const size_t szBNC = (size_t)NB * NSP * NC * 2;  // 8.4 MB (bf16)
  unsigned short* xn = (unsigned short*)wst;
  unsigned short* q  = (unsigned short*)(wst + szBNC);    // frag-tiled, pre-scaled
  unsigned short* k  = (unsigned short*)(wst + 2 * szBNC);// frag-tiled
  unsigned short* v  = (unsigned short*)(wst + 3 * szBNC);// V^T frag-tiled
  unsigned short* Opart = (unsigned short*)(wst + 4 * szBNC);  // 33.6 MB
  float* Lpart = (float*)(wst + 4 * szBNC + (size_t)JSPLIT * NROWS * NC * 2);  // 256 KB
  // peak ws: 68.4 MB (proven-safe <= 76.6 MB)

  cvt2_kernel<<<dim3(4 * NC * NC / 1024), 256, 0, stream>>>(qkv_w, proj_w, wq, wp);
  gn_kernel<<<dim3(NB * NG), 256, 0, stream>>>(x, norm_w, norm_b, xn);
  qkv_gemm<<<dim3(NSP / 128, 6, NB), 256, 0, stream>>>(wq, xn, qkv_b, q, k, v);
  flash9_kernel<<<dim3(NSP / 128, NB, JSPLIT), 256, 0, stream>>>(q, k, v, Opart, Lpart);
  proj_gemm<<<dim3(NSP / 128, NC / 128, NB), 256, 0, stream>>>(
      wp, Opart, Lpart, proj_b, x, out);
}

// Round 6
// 214.118 us; speedup vs baseline: 1.4125x; 1.4125x over previous
//
#include <hip/hip_runtime.h>
#include <stdint.h>
#include <stddef.h>

#define NB 4
#define NC 256
#define NSP 4096
#define NG 32
#define CPG 8
#define GEPS 1e-5f
#define SCALE 0.0625f            // d^-0.5, d=256
#define SCALE_L2E 0.090168440f   // SCALE * log2(e): Q pre-scale so exp(S)=exp2(S')
#define NROWS (NB * NSP)  // 16384 global q-rows
#define JSPLIT 4

typedef __attribute__((ext_vector_type(8))) short s8v;
typedef __attribute__((ext_vector_type(4))) float f4v;
typedef __attribute__((ext_vector_type(16))) float f16v;
typedef __attribute__((ext_vector_type(4))) unsigned short us4v;
typedef __attribute__((ext_vector_type(4))) unsigned int u4v;

__device__ __forceinline__ float b2f(unsigned short h) {
  union { unsigned u; float f; } x; x.u = ((unsigned)h) << 16; return x.f;
}
__device__ __forceinline__ unsigned short f2b(float f) {
  union { float f; unsigned u; } x; x.f = f;
  unsigned r = x.u + 0x7fffu + ((x.u >> 16) & 1u);
  return (unsigned short)(r >> 16);
}
// pack two f32 -> one u32 of 2 bf16 (RTZ), lo in low half
__device__ __forceinline__ unsigned packbf(float lo, float hi) {
  union { float f; unsigned u; } a, b; a.f = lo; b.f = hi;
  return (b.u & 0xffff0000u) | (a.u >> 16);
}

// ---- fp32 -> bf16 convert, both weight blobs in one launch ----
__global__ __launch_bounds__(256) void cvt2_kernel(
    const float* __restrict__ qw, const float* __restrict__ pw,
    unsigned short* __restrict__ wq, unsigned short* __restrict__ wp) {
  int i = (blockIdx.x * 256 + threadIdx.x) * 4;
  const float* src; unsigned short* dst; int j;
  if (i < 3 * NC * NC) { src = qw; dst = wq; j = i; }
  else { src = pw; dst = wp; j = i - 3 * NC * NC; }
  float4 v = *(const float4*)(src + j);
  us4v p;
  p[0] = f2b(v.x); p[1] = f2b(v.y); p[2] = f2b(v.z); p[3] = f2b(v.w);
  *(us4v*)(dst + j) = p;
}

// -------------------- GroupNorm: x fp32 (B,C,N) -> xn bf16 (B,N,C) --------------------
__global__ __launch_bounds__(256) void gn_kernel(
    const float* __restrict__ x, const float* __restrict__ w,
    const float* __restrict__ bias, unsigned short* __restrict__ xn) {
  int b = blockIdx.x >> 5;
  int g = blockIdx.x & 31;
  const float* xp = x + ((size_t)b * NC + (size_t)g * CPG) * NSP;
  int t = threadIdx.x;
  float s = 0.f, ss = 0.f;
  for (int i = 4 * t; i < CPG * NSP; i += 1024) {
    float4 v = *(const float4*)(xp + i);
    s += v.x + v.y + v.z + v.w;
    ss += v.x * v.x + v.y * v.y + v.z * v.z + v.w * v.w;
  }
  __shared__ float r1[256], r2[256];
  r1[t] = s; r2[t] = ss;
  __syncthreads();
  for (int off = 128; off > 0; off >>= 1) {
    if (t < off) { r1[t] += r1[t + off]; r2[t] += r2[t + off]; }
    __syncthreads();
  }
  float mean = r1[0] * (1.f / (CPG * NSP));
  float var  = r2[0] * (1.f / (CPG * NSP)) - mean * mean;
  float rstd = rsqrtf(var + GEPS);
  float wv[CPG], bv[CPG];
  for (int c = 0; c < CPG; c++) {
    wv[c] = w[g * CPG + c] * rstd;
    bv[c] = bias[g * CPG + c] - mean * wv[c];
  }
  for (int n = t; n < NSP; n += 256) {
    s8v pk;
    for (int c = 0; c < CPG; c++) {
      float v = xp[(size_t)c * NSP + n];
      ((unsigned short*)&pk)[c] = f2b(v * wv[c] + bv[c]);
    }
    *(s8v*)(xn + ((size_t)(b * NSP + n) * NC + g * CPG)) = pk;
  }
}

// ---- Fused QKV GEMM: one launch, grid (NSP/128, 6, NB). sec = y>>1 (0=q,1=k,2=v). ----
// Swizzles for 32x32x16 flash:
//  Q/K (sec<2): per 32-token tile (8192 shorts), element (tok, d) at
//    (d>>4)*512 + ((d>>3)&1)*256 + (tok&31)*8 + (d&7)   [A/B-frag linear, lane=hi*32+tok]
//  V  (sec=2): per 32-token tile, element (tok, d) at
//    (d>>5)*1024 + ((tok>>4)&1)*512 + ((tok>>3)&1)*256 + (d&31)*8 + (tok&7)  [V^T A-frag]
// Q pre-scaled by SCALE*log2(e) so flash uses native exp2.
__global__ __launch_bounds__(256) void qkv_gemm(
    const unsigned short* __restrict__ W, const unsigned short* __restrict__ xnG,
    const float* __restrict__ qkvb,
    unsigned short* __restrict__ q, unsigned short* __restrict__ k,
    unsigned short* __restrict__ v) {
  const int sec = blockIdx.y >> 1;
  const int m0 = (blockIdx.y & 1) * 128;
  const int n0 = blockIdx.x * 128;
  const unsigned short* A  = W + (size_t)sec * NC * NC;
  const unsigned short* Bt = xnG + (size_t)blockIdx.z * NSP * NC;
  unsigned short* dst = (sec == 0 ? q : (sec == 1 ? k : v)) + (size_t)blockIdx.z * NSP * NC;
  const float scl = (sec == 0) ? SCALE_L2E : 1.f;

  __shared__ unsigned short As[128 * 32], Bs[128 * 32];
  const int t = threadIdx.x;
  const int lane = t & 63, wave = t >> 6;
  const int wm = (wave >> 1) * 64, wn = (wave & 1) * 64;
  const int l16 = lane & 15, quad = lane >> 4;
  const int srow = t >> 2, skc = (t & 3) * 8;

  f4v acc[4][4];
  for (int mi = 0; mi < 4; mi++)
    for (int ni = 0; ni < 4; ni++)
      acc[mi][ni] = (f4v){0.f, 0.f, 0.f, 0.f};

  const unsigned short* Ag0 = A  + (size_t)(m0 + srow) * NC + skc;
  const unsigned short* Ag1 = A  + (size_t)(m0 + srow + 64) * NC + skc;
  const unsigned short* Bg0 = Bt + (size_t)(n0 + srow) * NC + skc;
  const unsigned short* Bg1 = Bt + (size_t)(n0 + srow + 64) * NC + skc;

  for (int k0 = 0; k0 < NC; k0 += 32) {
    s8v a0 = *(const s8v*)(Ag0 + k0);
    s8v a1 = *(const s8v*)(Ag1 + k0);
    s8v b0 = *(const s8v*)(Bg0 + k0);
    s8v b1 = *(const s8v*)(Bg1 + k0);
    __syncthreads();
    *(s8v*)(As + srow * 32 + skc) = a0;
    *(s8v*)(As + (srow + 64) * 32 + skc) = a1;
    *(s8v*)(Bs + srow * 32 + skc) = b0;
    *(s8v*)(Bs + (srow + 64) * 32 + skc) = b1;
    __syncthreads();
    s8v af[4], bfr[4];
    for (int mi = 0; mi < 4; mi++)
      af[mi] = *(const s8v*)(As + (wm + mi * 16 + l16) * 32 + quad * 8);
    for (int ni = 0; ni < 4; ni++)
      bfr[ni] = *(const s8v*)(Bs + (wn + ni * 16 + l16) * 32 + quad * 8);
    for (int mi = 0; mi < 4; mi++)
      for (int ni = 0; ni < 4; ni++)
        acc[mi][ni] = __builtin_amdgcn_mfma_f32_16x16x32_bf16(af[mi], bfr[ni], acc[mi][ni], 0, 0, 0);
  }

  for (int mi = 0; mi < 4; mi++) {
    const int rb = m0 + wm + mi * 16 + quad * 4;   // d within section (0..255)
    for (int ni = 0; ni < 4; ni++) {
      const int col = n0 + wn + ni * 16 + l16;     // token
      f4v a = acc[mi][ni];
      if (sec < 2) {  // Q/K frag tile: rb&7 in {0,4}, octet-constant -> 8B store
        us4v pk;
        for (int r = 0; r < 4; r++)
          pk[r] = f2b((a[r] + qkvb[sec * NC + rb + r]) * scl);
        const size_t off = (size_t)(col >> 5) * 8192 + (rb >> 4) * 512 +
                           ((rb >> 3) & 1) * 256 + (col & 31) * 8 + (rb & 7);
        *(us4v*)(dst + off) = pk;
      } else {        // V^T frag tile: d varies per r -> scalar stores
        for (int r = 0; r < 4; r++) {
          const int d = rb + r;
          const size_t off = (size_t)(col >> 5) * 8192 + (d >> 5) * 1024 +
                             ((col >> 4) & 1) * 512 + ((col >> 3) & 1) * 256 +
                             (d & 31) * 8 + (col & 7);
          dst[off] = f2b(a[r] + qkvb[2 * NC + d]);
        }
      }
    }
  }
}

// ---- Flash v10: v6 structure (best, 78us) + T5 setprio + native exp2 ----
// grid (NSP/128, NB, JSPLIT), 256 thr, 2 blocks/CU, 2 waves/SIMD.
__global__ __launch_bounds__(256, 2) void flash10_kernel(
    const unsigned short* __restrict__ q, const unsigned short* __restrict__ k,
    const unsigned short* __restrict__ v, unsigned short* __restrict__ Opart,
    float* __restrict__ Lpart) {
  const int qt = blockIdx.x, b = blockIdx.y, js = blockIdx.z;
  const size_t sNC = (size_t)NSP * NC;
  const unsigned short* qb = q + b * sNC;
  const unsigned short* kb = k + b * sNC;
  const unsigned short* vb = v + b * sNC;
  const int t = threadIdx.x, lane = t & 63, w = t >> 6;

  __shared__ unsigned short K_lds[2][16 * 512];  // 32 j x 256 d, frag-linear
  __shared__ unsigned short V_lds[2][16 * 512];  // 32 j x 256 d, V^T frag-linear

  f16v zero16;
  #pragma unroll
  for (int r = 0; r < 16; r++) zero16[r] = 0.f;

  // Q resident as B-frags: wave w owns 32-token tile qt*4 + w
  s8v qf[16];
  {
    const unsigned short* qp = qb + (size_t)(qt * 4 + w) * 8192 + lane * 8;
    #pragma unroll
    for (int kc = 0; kc < 16; kc++)
      qf[kc] = *(const s8v*)(qp + kc * 512);
  }

  f16v accO[8];
  #pragma unroll
  for (int dt = 0; dt < 8; dt++) accO[dt] = zero16;
  float l4[4] = {0.f, 0.f, 0.f, 0.f};

  const int jbeg = js * (NSP / JSPLIT);
  const int NT = (NSP / JSPLIT) / 32;

  auto stage = [&](int j0, int bufsel) {
    const size_t tb = (size_t)(j0 >> 5) * 16;
    #pragma unroll
    for (int ii = 0; ii < 8; ii++) {
      const int idx = w * 8 + ii;  // waves 0-1: K chunks 0..15; waves 2-3: V chunks
      const unsigned short* gp;
      unsigned short* ld;
      if (idx < 16) {
        gp = kb + (tb + idx) * 512 + lane * 8;
        ld = &K_lds[bufsel][idx * 512];
      } else {
        const int dt = idx - 16;
        gp = vb + (tb + dt) * 512 + lane * 8;
        ld = &V_lds[bufsel][dt * 512];
      }
      __builtin_amdgcn_global_load_lds(
          (const __attribute__((address_space(1))) unsigned int*)gp,
          (__attribute__((address_space(3))) unsigned int*)ld, 16, 0, 0);
    }
  };

  stage(jbeg, 0);
  for (int jt = 0; jt < NT; jt++) {
    __syncthreads();
    if (jt + 1 < NT) stage(jbeg + (jt + 1) * 32, (jt + 1) & 1);
    const unsigned short* Kc = K_lds[jt & 1];
    const unsigned short* Vc = V_lds[jt & 1];

    // S^T = K . Q^T over d = 256 (16 k-steps)
    f16v accS = zero16;
    __builtin_amdgcn_s_setprio(1);
    #pragma unroll
    for (int kc = 0; kc < 16; kc++) {
      s8v kf = *(const s8v*)(Kc + kc * 512 + lane * 8);
      accS = __builtin_amdgcn_mfma_f32_32x32x16_bf16(kf, qf[kc], accS, 0, 0, 0);
    }
    __builtin_amdgcn_s_setprio(0);

    // p = exp2(s'): q pre-scaled by SCALE*log2e, no max (80-sigma headroom)
    float p[16];
    #pragma unroll
    for (int r = 0; r < 16; r++) {
      p[r] = exp2f(accS[r]);
      l4[r & 3] += p[r];
    }

    // Repack P rows (j) into PV B-frags (T12: packbf + permlane32_swap)
    u4v pw0, pw1;
    {
      unsigned a0 = packbf(p[0], p[1]),   b0 = packbf(p[4], p[5]);
      asm("v_permlane32_swap_b32 %0, %1" : "+v"(a0), "+v"(b0));
      unsigned a1 = packbf(p[2], p[3]),   b1 = packbf(p[6], p[7]);
      asm("v_permlane32_swap_b32 %0, %1" : "+v"(a1), "+v"(b1));
      unsigned a2 = packbf(p[8], p[9]),   b2 = packbf(p[12], p[13]);
      asm("v_permlane32_swap_b32 %0, %1" : "+v"(a2), "+v"(b2));
      unsigned a3 = packbf(p[10], p[11]), b3 = packbf(p[14], p[15]);
      asm("v_permlane32_swap_b32 %0, %1" : "+v"(a3), "+v"(b3));
      pw0[0] = a0; pw0[1] = a1; pw0[2] = b0; pw0[3] = b1;  // j-half 0 (j=0..15)
      pw1[0] = a2; pw1[1] = a3; pw1[2] = b2; pw1[3] = b3;  // j-half 1 (j=16..31)
    }
    const s8v pb0 = __builtin_bit_cast(s8v, pw0);
    const s8v pb1 = __builtin_bit_cast(s8v, pw1);

    // out^T += V^T . P^T : 8 d-tiles x 2 j-halves
    __builtin_amdgcn_s_setprio(1);
    #pragma unroll
    for (int dt = 0; dt < 8; dt++) {
      s8v vf0 = *(const s8v*)(Vc + dt * 1024 + lane * 8);
      s8v vf1 = *(const s8v*)(Vc + dt * 1024 + 512 + lane * 8);
      accO[dt] = __builtin_amdgcn_mfma_f32_32x32x16_bf16(vf0, pb0, accO[dt], 0, 0, 0);
      accO[dt] = __builtin_amdgcn_mfma_f32_32x32x16_bf16(vf1, pb1, accO[dt], 0, 0, 0);
    }
    __builtin_amdgcn_s_setprio(0);
  }

  // epilogue: lane owns q = lane&31; combine lane halves, write L + O^T
  float l_acc = l4[0] + l4[1] + l4[2] + l4[3];
  const float ltot = l_acc + __shfl_xor(l_acc, 32, 64);
  const int qrow = b * NSP + qt * 128 + w * 32 + (lane & 31);
  if (lane < 32)
    Lpart[(size_t)js * NROWS + qrow] = ltot;

  unsigned short* Op = Opart + ((size_t)js * NROWS + qrow) * NC;
  const int hi = lane >> 5;
  #pragma unroll
  for (int dt = 0; dt < 8; dt++) {
    #pragma unroll
    for (int g = 0; g < 4; g++) {
      us4v pk;
      #pragma unroll
      for (int r = 0; r < 4; r++)
        pk[r] = f2b(accO[dt][g * 4 + r]);
      // d = dt*32 + g*8 + hi*4 + r
      *(us4v*)(Op + dt * 32 + g * 8 + hi * 4) = pk;
    }
  }
}

// ---- Fused proj GEMM with inline merge of JSPLIT partials ----
__global__ __launch_bounds__(256) void proj_gemm(
    const unsigned short* __restrict__ Wp, const unsigned short* __restrict__ Opart,
    const float* __restrict__ Lpart, const float* __restrict__ pb,
    const float* __restrict__ x, float* __restrict__ out) {
  const int z = blockIdx.z, m0 = blockIdx.y * 128, n0 = blockIdx.x * 128;
  __shared__ unsigned short As[128 * 32], Bs[128 * 32];
  const int t = threadIdx.x;
  const int lane = t & 63, wave = t >> 6;
  const int wm = (wave >> 1) * 64, wn = (wave & 1) * 64;
  const int l16 = lane & 15, quad = lane >> 4;
  const int srow = t >> 2, skc = (t & 3) * 8;

  const int prow0 = z * NSP + n0 + srow;
  const int prow1 = prow0 + 64;
  float ls0 = 0.f, ls1 = 0.f;
  for (int js = 0; js < JSPLIT; js++) {
    ls0 += Lpart[(size_t)js * NROWS + prow0];
    ls1 += Lpart[(size_t)js * NROWS + prow1];
  }
  const float inv0 = 1.f / ls0, inv1 = 1.f / ls1;

  f4v acc[4][4];
  for (int mi = 0; mi < 4; mi++)
    for (int ni = 0; ni < 4; ni++)
      acc[mi][ni] = (f4v){0.f, 0.f, 0.f, 0.f};

  const unsigned short* Ag0 = Wp + (size_t)(m0 + srow) * NC + skc;
  const unsigned short* Ag1 = Wp + (size_t)(m0 + srow + 64) * NC + skc;

  for (int k0 = 0; k0 < NC; k0 += 32) {
    s8v a0 = *(const s8v*)(Ag0 + k0);
    s8v a1 = *(const s8v*)(Ag1 + k0);
    float bv0[8], bv1[8];
    for (int e = 0; e < 8; e++) { bv0[e] = 0.f; bv1[e] = 0.f; }
    for (int js = 0; js < JSPLIT; js++) {
      const s8v o0 = *(const s8v*)(Opart + ((size_t)js * NROWS + prow0) * NC + k0 + skc);
      const s8v o1 = *(const s8v*)(Opart + ((size_t)js * NROWS + prow1) * NC + k0 + skc);
      for (int e = 0; e < 8; e++) {
        bv0[e] += b2f(((const unsigned short*)&o0)[e]);
        bv1[e] += b2f(((const unsigned short*)&o1)[e]);
      }
    }
    s8v b0, b1;
    for (int e = 0; e < 8; e++) {
      ((unsigned short*)&b0)[e] = f2b(bv0[e] * inv0);
      ((unsigned short*)&b1)[e] = f2b(bv1[e] * inv1);
    }
    __syncthreads();
    *(s8v*)(As + srow * 32 + skc) = a0;
    *(s8v*)(As + (srow + 64) * 32 + skc) = a1;
    *(s8v*)(Bs + srow * 32 + skc) = b0;
    *(s8v*)(Bs + (srow + 64) * 32 + skc) = b1;
    __syncthreads();
    s8v af[4], bfr[4];
    for (int mi = 0; mi < 4; mi++)
      af[mi] = *(const s8v*)(As + (wm + mi * 16 + l16) * 32 + quad * 8);
    for (int ni = 0; ni < 4; ni++)
      bfr[ni] = *(const s8v*)(Bs + (wn + ni * 16 + l16) * 32 + quad * 8);
    for (int mi = 0; mi < 4; mi++)
      for (int ni = 0; ni < 4; ni++)
        acc[mi][ni] = __builtin_amdgcn_mfma_f32_16x16x32_bf16(af[mi], bfr[ni], acc[mi][ni], 0, 0, 0);
  }

  float* C = out + (size_t)z * NC * NSP;
  const float* R = x + (size_t)z * NC * NSP;
  for (int mi = 0; mi < 4; mi++) {
    const int rb = m0 + wm + mi * 16 + quad * 4;
    for (int ni = 0; ni < 4; ni++) {
      const int col = n0 + wn + ni * 16 + l16;
      f4v a = acc[mi][ni];
      for (int r = 0; r < 4; r++)
        C[(size_t)(rb + r) * NSP + col] =
            a[r] + pb[rb + r] + R[(size_t)(rb + r) * NSP + col];
    }
  }
}

extern "C" void kernel_launch(void* const* d_in, const int* in_sizes, int n_in,
                              void* d_out, int out_size, void* d_ws, size_t ws_size,
                              hipStream_t stream) {
  const float* x      = (const float*)d_in[0];
  const float* norm_w = (const float*)d_in[1];
  const float* norm_b = (const float*)d_in[2];
  const float* qkv_w  = (const float*)d_in[3];
  const float* qkv_b  = (const float*)d_in[4];
  const float* proj_w = (const float*)d_in[5];
  const float* proj_b = (const float*)d_in[6];
  float* out = (float*)d_out;  // fp32 output

  char* ws = (char*)d_ws;
  unsigned short* wq = (unsigned short*)ws;                     // 384 KB
  unsigned short* wp = (unsigned short*)(ws + 3 * NC * NC * 2); // 128 KB
  char* wst = ws + (1 << 20);
  const size_t szBNC = (size_t)NB * NSP * NC * 2;  // 8.4 MB (bf16)
  unsigned short* xn = (unsigned short*)wst;
  unsigned short* q  = (unsigned short*)(wst + szBNC);    // frag-tiled, pre-scaled
  unsigned short* k  = (unsigned short*)(wst + 2 * szBNC);// frag-tiled
  unsigned short* v  = (unsigned short*)(wst + 3 * szBNC);// V^T frag-tiled
  unsigned short* Opart = (unsigned short*)(wst + 4 * szBNC);  // 33.6 MB
  float* Lpart = (float*)(wst + 4 * szBNC + (size_t)JSPLIT * NROWS * NC * 2);  // 256 KB
  // peak ws: 68.4 MB (proven-safe <= 76.6 MB)

  cvt2_kernel<<<dim3(4 * NC * NC / 1024), 256, 0, stream>>>(qkv_w, proj_w, wq, wp);
  gn_kernel<<<dim3(NB * NG), 256, 0, stream>>>(x, norm_w, norm_b, xn);
  qkv_gemm<<<dim3(NSP / 128, 6, NB), 256, 0, stream>>>(wq, xn, qkv_b, q, k, v);
  flash10_kernel<<<dim3(NSP / 128, NB, JSPLIT), 256, 0, stream>>>(q, k, v, Opart, Lpart);
  proj_gemm<<<dim3(NSP / 128, NC / 128, NB), 256, 0, stream>>>(
      wp, Opart, Lpart, proj_b, x, out);
}

// Round 7
// 210.286 us; speedup vs baseline: 1.4383x; 1.0182x over previous
//
#include <hip/hip_runtime.h>
#include <stdint.h>
#include <stddef.h>

#define NB 4
#define NC 256
#define NSP 4096
#define NG 32
#define CPG 8
#define GEPS 1e-5f
#define SCALE 0.0625f  // d^-0.5, d=256
#define NROWS (NB * NSP)  // 16384 global q-rows
#define JSPLIT 4

typedef __attribute__((ext_vector_type(8))) short s8v;
typedef __attribute__((ext_vector_type(4))) float f4v;
typedef __attribute__((ext_vector_type(16))) float f16v;
typedef __attribute__((ext_vector_type(4))) unsigned short us4v;
typedef __attribute__((ext_vector_type(4))) unsigned int u4v;

__device__ __forceinline__ float b2f(unsigned short h) {
  union { unsigned u; float f; } x; x.u = ((unsigned)h) << 16; return x.f;
}
__device__ __forceinline__ unsigned short f2b(float f) {
  union { float f; unsigned u; } x; x.f = f;
  unsigned r = x.u + 0x7fffu + ((x.u >> 16) & 1u);
  return (unsigned short)(r >> 16);
}
__device__ __forceinline__ unsigned short f2b_rtz(float f) {
  union { float f; unsigned u; } x; x.f = f;
  return (unsigned short)(x.u >> 16);
}
// pack two f32 -> one u32 of 2 bf16 (RTZ), lo in low half
__device__ __forceinline__ unsigned packbf(float lo, float hi) {
  union { float f; unsigned u; } a, b; a.f = lo; b.f = hi;
  return (b.u & 0xffff0000u) | (a.u >> 16);
}
// pack 8 fp32 (two float4) -> s8v of bf16 (round-nearest, same as old cvt2)
__device__ __forceinline__ s8v pack8(float4 lo, float4 hi) {
  s8v r;
  ((unsigned short*)&r)[0] = f2b(lo.x);
  ((unsigned short*)&r)[1] = f2b(lo.y);
  ((unsigned short*)&r)[2] = f2b(lo.z);
  ((unsigned short*)&r)[3] = f2b(lo.w);
  ((unsigned short*)&r)[4] = f2b(hi.x);
  ((unsigned short*)&r)[5] = f2b(hi.y);
  ((unsigned short*)&r)[6] = f2b(hi.z);
  ((unsigned short*)&r)[7] = f2b(hi.w);
  return r;
}

// ---- GroupNorm one-pass: stage fp32 tile in LDS (128KB), x read ONCE ----
// grid (NB*NG) = 128 blocks, 512 threads, 1 block/CU (LDS-capped).
__global__ __launch_bounds__(512) void gn_kernel(
    const float* __restrict__ x, const float* __restrict__ w,
    const float* __restrict__ bias, unsigned short* __restrict__ xn) {
  int b = blockIdx.x >> 5;
  int g = blockIdx.x & 31;
  const float* xp = x + ((size_t)b * NC + (size_t)g * CPG) * NSP;
  int t = threadIdx.x;

  __shared__ float xs[CPG * NSP];   // 128 KB
  __shared__ float r1[512], r2[512];

  float s = 0.f, ss = 0.f;
  for (int i = 4 * t; i < CPG * NSP; i += 2048) {
    float4 v = *(const float4*)(xp + i);
    *(float4*)(xs + i) = v;
    s += v.x + v.y + v.z + v.w;
    ss += v.x * v.x + v.y * v.y + v.z * v.z + v.w * v.w;
  }
  r1[t] = s; r2[t] = ss;
  __syncthreads();
  for (int off = 256; off > 0; off >>= 1) {
    if (t < off) { r1[t] += r1[t + off]; r2[t] += r2[t + off]; }
    __syncthreads();
  }
  float mean = r1[0] * (1.f / (CPG * NSP));
  float var  = r2[0] * (1.f / (CPG * NSP)) - mean * mean;
  float rstd = rsqrtf(var + GEPS);
  float wv[CPG], bv[CPG];
  for (int c = 0; c < CPG; c++) {
    wv[c] = w[g * CPG + c] * rstd;
    bv[c] = bias[g * CPG + c] - mean * wv[c];
  }
  for (int n = t; n < NSP; n += 512) {
    s8v pk;
    for (int c = 0; c < CPG; c++) {
      float v = xs[c * NSP + n];
      ((unsigned short*)&pk)[c] = f2b(v * wv[c] + bv[c]);
    }
    *(s8v*)(xn + ((size_t)(b * NSP + n) * NC + g * CPG)) = pk;
  }
}

// ---- Fused QKV GEMM: fp32 W converted inline (cvt2 kernel eliminated). ----
// grid (NSP/128, 6, NB). sec = y>>1 (0=q,1=k,2=v).
// Swizzles for 32x32x16 flash:
//  Q/K (sec<2): per 32-token tile (8192 shorts), element (tok, d) at
//    (d>>4)*512 + ((d>>3)&1)*256 + (tok&31)*8 + (d&7)   [A/B-frag linear, lane=hi*32+tok]
//  V  (sec=2): per 32-token tile, element (tok, d) at
//    (d>>5)*1024 + ((tok>>4)&1)*512 + ((tok>>3)&1)*256 + (d&31)*8 + (tok&7)  [V^T A-frag]
__global__ __launch_bounds__(256) void qkv_gemm(
    const float* __restrict__ Wf, const unsigned short* __restrict__ xnG,
    const float* __restrict__ qkvb,
    unsigned short* __restrict__ q, unsigned short* __restrict__ k,
    unsigned short* __restrict__ v) {
  const int sec = blockIdx.y >> 1;
  const int m0 = (blockIdx.y & 1) * 128;
  const int n0 = blockIdx.x * 128;
  const float* A = Wf + (size_t)sec * NC * NC;
  const unsigned short* Bt = xnG + (size_t)blockIdx.z * NSP * NC;
  unsigned short* dst = (sec == 0 ? q : (sec == 1 ? k : v)) + (size_t)blockIdx.z * NSP * NC;
  const float scl = (sec == 0) ? SCALE : 1.f;

  __shared__ unsigned short As[128 * 32], Bs[128 * 32];
  const int t = threadIdx.x;
  const int lane = t & 63, wave = t >> 6;
  const int wm = (wave >> 1) * 64, wn = (wave & 1) * 64;
  const int l16 = lane & 15, quad = lane >> 4;
  const int srow = t >> 2, skc = (t & 3) * 8;

  f4v acc[4][4];
  for (int mi = 0; mi < 4; mi++)
    for (int ni = 0; ni < 4; ni++)
      acc[mi][ni] = (f4v){0.f, 0.f, 0.f, 0.f};

  const float* Ag0 = A + (size_t)(m0 + srow) * NC + skc;
  const float* Ag1 = A + (size_t)(m0 + srow + 64) * NC + skc;
  const unsigned short* Bg0 = Bt + (size_t)(n0 + srow) * NC + skc;
  const unsigned short* Bg1 = Bt + (size_t)(n0 + srow + 64) * NC + skc;

  for (int k0 = 0; k0 < NC; k0 += 32) {
    s8v a0 = pack8(*(const float4*)(Ag0 + k0), *(const float4*)(Ag0 + k0 + 4));
    s8v a1 = pack8(*(const float4*)(Ag1 + k0), *(const float4*)(Ag1 + k0 + 4));
    s8v b0 = *(const s8v*)(Bg0 + k0);
    s8v b1 = *(const s8v*)(Bg1 + k0);
    __syncthreads();
    *(s8v*)(As + srow * 32 + skc) = a0;
    *(s8v*)(As + (srow + 64) * 32 + skc) = a1;
    *(s8v*)(Bs + srow * 32 + skc) = b0;
    *(s8v*)(Bs + (srow + 64) * 32 + skc) = b1;
    __syncthreads();
    s8v af[4], bfr[4];
    for (int mi = 0; mi < 4; mi++)
      af[mi] = *(const s8v*)(As + (wm + mi * 16 + l16) * 32 + quad * 8);
    for (int ni = 0; ni < 4; ni++)
      bfr[ni] = *(const s8v*)(Bs + (wn + ni * 16 + l16) * 32 + quad * 8);
    for (int mi = 0; mi < 4; mi++)
      for (int ni = 0; ni < 4; ni++)
        acc[mi][ni] = __builtin_amdgcn_mfma_f32_16x16x32_bf16(af[mi], bfr[ni], acc[mi][ni], 0, 0, 0);
  }

  for (int mi = 0; mi < 4; mi++) {
    const int rb = m0 + wm + mi * 16 + quad * 4;   // d within section (0..255)
    for (int ni = 0; ni < 4; ni++) {
      const int col = n0 + wn + ni * 16 + l16;     // token
      f4v a = acc[mi][ni];
      if (sec < 2) {  // Q/K frag tile: rb&7 in {0,4}, octet-constant -> 8B store
        us4v pk;
        for (int r = 0; r < 4; r++)
          pk[r] = f2b((a[r] + qkvb[sec * NC + rb + r]) * scl);
        const size_t off = (size_t)(col >> 5) * 8192 + (rb >> 4) * 512 +
                           ((rb >> 3) & 1) * 256 + (col & 31) * 8 + (rb & 7);
        *(us4v*)(dst + off) = pk;
      } else {        // V^T frag tile: d varies per r -> scalar stores
        for (int r = 0; r < 4; r++) {
          const int d = rb + r;
          const size_t off = (size_t)(col >> 5) * 8192 + (d >> 5) * 1024 +
                             ((col >> 4) & 1) * 512 + ((col >> 3) & 1) * 256 +
                             (d & 31) * 8 + (col & 7);
          dst[off] = f2b(a[r] + qkvb[2 * NC + d]);
        }
      }
    }
  }
}

// ---- Flash v11 == v6 exact (best measured: 78.3us): swapped-QK 32x32x16,
// in-register softmax, __expf, no setprio. grid (NSP/128, NB, JSPLIT), 256 thr.
__global__ __launch_bounds__(256, 2) void flash11_kernel(
    const unsigned short* __restrict__ q, const unsigned short* __restrict__ k,
    const unsigned short* __restrict__ v, unsigned short* __restrict__ Opart,
    float* __restrict__ Lpart) {
  const int qt = blockIdx.x, b = blockIdx.y, js = blockIdx.z;
  const size_t sNC = (size_t)NSP * NC;
  const unsigned short* qb = q + b * sNC;
  const unsigned short* kb = k + b * sNC;
  const unsigned short* vb = v + b * sNC;
  const int t = threadIdx.x, lane = t & 63, w = t >> 6;

  __shared__ unsigned short K_lds[2][16 * 512];  // 32 j x 256 d, frag-linear
  __shared__ unsigned short V_lds[2][16 * 512];  // 32 j x 256 d, V^T frag-linear

  f16v zero16;
  #pragma unroll
  for (int r = 0; r < 16; r++) zero16[r] = 0.f;

  // Q resident as B-frags: wave w owns 32-token tile qt*4 + w
  s8v qf[16];
  {
    const unsigned short* qp = qb + (size_t)(qt * 4 + w) * 8192 + lane * 8;
    #pragma unroll
    for (int kc = 0; kc < 16; kc++)
      qf[kc] = *(const s8v*)(qp + kc * 512);
  }

  f16v accO[8];
  #pragma unroll
  for (int dt = 0; dt < 8; dt++) accO[dt] = zero16;
  float l4[4] = {0.f, 0.f, 0.f, 0.f};

  const int jbeg = js * (NSP / JSPLIT);
  const int NT = (NSP / JSPLIT) / 32;

  auto stage = [&](int j0, int bufsel) {
    const size_t tb = (size_t)(j0 >> 5) * 16;
    #pragma unroll
    for (int ii = 0; ii < 8; ii++) {
      const int idx = w * 8 + ii;  // waves 0-1: K chunks 0..15; waves 2-3: V chunks
      const unsigned short* gp;
      unsigned short* ld;
      if (idx < 16) {
        gp = kb + (tb + idx) * 512 + lane * 8;
        ld = &K_lds[bufsel][idx * 512];
      } else {
        const int dt = idx - 16;
        gp = vb + (tb + dt) * 512 + lane * 8;
        ld = &V_lds[bufsel][dt * 512];
      }
      __builtin_amdgcn_global_load_lds(
          (const __attribute__((address_space(1))) unsigned int*)gp,
          (__attribute__((address_space(3))) unsigned int*)ld, 16, 0, 0);
    }
  };

  stage(jbeg, 0);
  for (int jt = 0; jt < NT; jt++) {
    __syncthreads();
    if (jt + 1 < NT) stage(jbeg + (jt + 1) * 32, (jt + 1) & 1);
    const unsigned short* Kc = K_lds[jt & 1];
    const unsigned short* Vc = V_lds[jt & 1];

    // S^T = K . Q^T over d = 256 (16 k-steps)
    f16v accS = zero16;
    #pragma unroll
    for (int kc = 0; kc < 16; kc++) {
      s8v kf = *(const s8v*)(Kc + kc * 512 + lane * 8);
      accS = __builtin_amdgcn_mfma_f32_32x32x16_bf16(kf, qf[kc], accS, 0, 0, 0);
    }

    // p = exp(s): q pre-scaled, no max (80-sigma headroom); l lane-local (col=q)
    float p[16];
    #pragma unroll
    for (int r = 0; r < 16; r++) {
      p[r] = __expf(accS[r]);
      l4[r & 3] += p[r];
    }

    // Repack P rows (j) into PV B-frags (T12: packbf + permlane32_swap)
    u4v pw0, pw1;
    {
      unsigned a0 = packbf(p[0], p[1]),   b0 = packbf(p[4], p[5]);
      asm("v_permlane32_swap_b32 %0, %1" : "+v"(a0), "+v"(b0));
      unsigned a1 = packbf(p[2], p[3]),   b1 = packbf(p[6], p[7]);
      asm("v_permlane32_swap_b32 %0, %1" : "+v"(a1), "+v"(b1));
      unsigned a2 = packbf(p[8], p[9]),   b2 = packbf(p[12], p[13]);
      asm("v_permlane32_swap_b32 %0, %1" : "+v"(a2), "+v"(b2));
      unsigned a3 = packbf(p[10], p[11]), b3 = packbf(p[14], p[15]);
      asm("v_permlane32_swap_b32 %0, %1" : "+v"(a3), "+v"(b3));
      pw0[0] = a0; pw0[1] = a1; pw0[2] = b0; pw0[3] = b1;  // j-half 0 (j=0..15)
      pw1[0] = a2; pw1[1] = a3; pw1[2] = b2; pw1[3] = b3;  // j-half 1 (j=16..31)
    }
    const s8v pb0 = __builtin_bit_cast(s8v, pw0);
    const s8v pb1 = __builtin_bit_cast(s8v, pw1);

    // out^T += V^T . P^T : 8 d-tiles x 2 j-halves
    #pragma unroll
    for (int dt = 0; dt < 8; dt++) {
      s8v vf0 = *(const s8v*)(Vc + dt * 1024 + lane * 8);
      s8v vf1 = *(const s8v*)(Vc + dt * 1024 + 512 + lane * 8);
      accO[dt] = __builtin_amdgcn_mfma_f32_32x32x16_bf16(vf0, pb0, accO[dt], 0, 0, 0);
      accO[dt] = __builtin_amdgcn_mfma_f32_32x32x16_bf16(vf1, pb1, accO[dt], 0, 0, 0);
    }
  }

  // epilogue: lane owns q = lane&31; combine lane halves, write L + O^T
  float l_acc = l4[0] + l4[1] + l4[2] + l4[3];
  const float ltot = l_acc + __shfl_xor(l_acc, 32, 64);
  const int qrow = b * NSP + qt * 128 + w * 32 + (lane & 31);
  if (lane < 32)
    Lpart[(size_t)js * NROWS + qrow] = ltot;

  unsigned short* Op = Opart + ((size_t)js * NROWS + qrow) * NC;
  const int hi = lane >> 5;
  #pragma unroll
  for (int dt = 0; dt < 8; dt++) {
    #pragma unroll
    for (int g = 0; g < 4; g++) {
      us4v pk;
      #pragma unroll
      for (int r = 0; r < 4; r++)
        pk[r] = f2b(accO[dt][g * 4 + r]);
      // d = dt*32 + g*8 + hi*4 + r
      *(us4v*)(Op + dt * 32 + g * 8 + hi * 4) = pk;
    }
  }
}

// ---- Fused proj GEMM: fp32 W inline-converted + inline merge of JSPLIT partials ----
__global__ __launch_bounds__(256) void proj_gemm(
    const float* __restrict__ Wpf, const unsigned short* __restrict__ Opart,
    const float* __restrict__ Lpart, const float* __restrict__ pb,
    const float* __restrict__ x, float* __restrict__ out) {
  const int z = blockIdx.z, m0 = blockIdx.y * 128, n0 = blockIdx.x * 128;
  __shared__ unsigned short As[128 * 32], Bs[128 * 32];
  const int t = threadIdx.x;
  const int lane = t & 63, wave = t >> 6;
  const int wm = (wave >> 1) * 64, wn = (wave & 1) * 64;
  const int l16 = lane & 15, quad = lane >> 4;
  const int srow = t >> 2, skc = (t & 3) * 8;

  const int prow0 = z * NSP + n0 + srow;
  const int prow1 = prow0 + 64;
  float ls0 = 0.f, ls1 = 0.f;
  for (int js = 0; js < JSPLIT; js++) {
    ls0 += Lpart[(size_t)js * NROWS + prow0];
    ls1 += Lpart[(size_t)js * NROWS + prow1];
  }
  const float inv0 = 1.f / ls0, inv1 = 1.f / ls1;

  f4v acc[4][4];
  for (int mi = 0; mi < 4; mi++)
    for (int ni = 0; ni < 4; ni++)
      acc[mi][ni] = (f4v){0.f, 0.f, 0.f, 0.f};

  const float* Ag0 = Wpf + (size_t)(m0 + srow) * NC + skc;
  const float* Ag1 = Wpf + (size_t)(m0 + srow + 64) * NC + skc;

  for (int k0 = 0; k0 < NC; k0 += 32) {
    s8v a0 = pack8(*(const float4*)(Ag0 + k0), *(const float4*)(Ag0 + k0 + 4));
    s8v a1 = pack8(*(const float4*)(Ag1 + k0), *(const float4*)(Ag1 + k0 + 4));
    float bv0[8], bv1[8];
    for (int e = 0; e < 8; e++) { bv0[e] = 0.f; bv1[e] = 0.f; }
    for (int js = 0; js < JSPLIT; js++) {
      const s8v o0 = *(const s8v*)(Opart + ((size_t)js * NROWS + prow0) * NC + k0 + skc);
      const s8v o1 = *(const s8v*)(Opart + ((size_t)js * NROWS + prow1) * NC + k0 + skc);
      for (int e = 0; e < 8; e++) {
        bv0[e] += b2f(((const unsigned short*)&o0)[e]);
        bv1[e] += b2f(((const unsigned short*)&o1)[e]);
      }
    }
    s8v b0, b1;
    for (int e = 0; e < 8; e++) {
      ((unsigned short*)&b0)[e] = f2b(bv0[e] * inv0);
      ((unsigned short*)&b1)[e] = f2b(bv1[e] * inv1);
    }
    __syncthreads();
    *(s8v*)(As + srow * 32 + skc) = a0;
    *(s8v*)(As + (srow + 64) * 32 + skc) = a1;
    *(s8v*)(Bs + srow * 32 + skc) = b0;
    *(s8v*)(Bs + (srow + 64) * 32 + skc) = b1;
    __syncthreads();
    s8v af[4], bfr[4];
    for (int mi = 0; mi < 4; mi++)
      af[mi] = *(const s8v*)(As + (wm + mi * 16 + l16) * 32 + quad * 8);
    for (int ni = 0; ni < 4; ni++)
      bfr[ni] = *(const s8v*)(Bs + (wn + ni * 16 + l16) * 32 + quad * 8);
    for (int mi = 0; mi < 4; mi++)
      for (int ni = 0; ni < 4; ni++)
        acc[mi][ni] = __builtin_amdgcn_mfma_f32_16x16x32_bf16(af[mi], bfr[ni], acc[mi][ni], 0, 0, 0);
  }

  float* C = out + (size_t)z * NC * NSP;
  const float* R = x + (size_t)z * NC * NSP;
  for (int mi = 0; mi < 4; mi++) {
    const int rb = m0 + wm + mi * 16 + quad * 4;
    for (int ni = 0; ni < 4; ni++) {
      const int col = n0 + wn + ni * 16 + l16;
      f4v a = acc[mi][ni];
      for (int r = 0; r < 4; r++)
        C[(size_t)(rb + r) * NSP + col] =
            a[r] + pb[rb + r] + R[(size_t)(rb + r) * NSP + col];
    }
  }
}

extern "C" void kernel_launch(void* const* d_in, const int* in_sizes, int n_in,
                              void* d_out, int out_size, void* d_ws, size_t ws_size,
                              hipStream_t stream) {
  const float* x      = (const float*)d_in[0];
  const float* norm_w = (const float*)d_in[1];
  const float* norm_b = (const float*)d_in[2];
  const float* qkv_w  = (const float*)d_in[3];
  const float* qkv_b  = (const float*)d_in[4];
  const float* proj_w = (const float*)d_in[5];
  const float* proj_b = (const float*)d_in[6];
  float* out = (float*)d_out;  // fp32 output

  char* ws = (char*)d_ws;
  char* wst = ws + (1 << 20);
  const size_t szBNC = (size_t)NB * NSP * NC * 2;  // 8.4 MB (bf16)
  unsigned short* xn = (unsigned short*)wst;
  unsigned short* q  = (unsigned short*)(wst + szBNC);    // frag-tiled, pre-scaled
  unsigned short* k  = (unsigned short*)(wst + 2 * szBNC);// frag-tiled
  unsigned short* v  = (unsigned short*)(wst + 3 * szBNC);// V^T frag-tiled
  unsigned short* Opart = (unsigned short*)(wst + 4 * szBNC);  // 33.6 MB
  float* Lpart = (float*)(wst + 4 * szBNC + (size_t)JSPLIT * NROWS * NC * 2);  // 256 KB
  // peak ws: 68.4 MB (proven-safe <= 76.6 MB)

  gn_kernel<<<dim3(NB * NG), 512, 0, stream>>>(x, norm_w, norm_b, xn);
  qkv_gemm<<<dim3(NSP / 128, 6, NB), 256, 0, stream>>>(qkv_w, xn, qkv_b, q, k, v);
  flash11_kernel<<<dim3(NSP / 128, NB, JSPLIT), 256, 0, stream>>>(q, k, v, Opart, Lpart);
  proj_gemm<<<dim3(NSP / 128, NC / 128, NB), 256, 0, stream>>>(
      proj_w, Opart, Lpart, proj_b, x, out);
}

// Round 8
// 207.261 us; speedup vs baseline: 1.4593x; 1.0146x over previous
//
#include <hip/hip_runtime.h>
#include <stdint.h>
#include <stddef.h>

#define NB 4
#define NC 256
#define NSP 4096
#define NG 32
#define CPG 8
#define GEPS 1e-5f
#define SCALE 0.0625f  // d^-0.5, d=256
#define NROWS (NB * NSP)  // 16384 global q-rows
#define JSPLIT 4

typedef __attribute__((ext_vector_type(8))) short s8v;
typedef __attribute__((ext_vector_type(4))) float f4v;
typedef __attribute__((ext_vector_type(16))) float f16v;
typedef __attribute__((ext_vector_type(4))) unsigned short us4v;
typedef __attribute__((ext_vector_type(4))) unsigned int u4v;

__device__ __forceinline__ float b2f(unsigned short h) {
  union { unsigned u; float f; } x; x.u = ((unsigned)h) << 16; return x.f;
}
__device__ __forceinline__ unsigned short f2b(float f) {
  union { float f; unsigned u; } x; x.f = f;
  unsigned r = x.u + 0x7fffu + ((x.u >> 16) & 1u);
  return (unsigned short)(r >> 16);
}
// pack two f32 -> one u32 of 2 bf16 (RTZ), lo in low half
__device__ __forceinline__ unsigned packbf(float lo, float hi) {
  union { float f; unsigned u; } a, b; a.f = lo; b.f = hi;
  return (b.u & 0xffff0000u) | (a.u >> 16);
}
// pack 8 fp32 (two float4) -> s8v of bf16 (round-nearest)
__device__ __forceinline__ s8v pack8(float4 lo, float4 hi) {
  s8v r;
  ((unsigned short*)&r)[0] = f2b(lo.x);
  ((unsigned short*)&r)[1] = f2b(lo.y);
  ((unsigned short*)&r)[2] = f2b(lo.z);
  ((unsigned short*)&r)[3] = f2b(lo.w);
  ((unsigned short*)&r)[4] = f2b(hi.x);
  ((unsigned short*)&r)[5] = f2b(hi.y);
  ((unsigned short*)&r)[6] = f2b(hi.z);
  ((unsigned short*)&r)[7] = f2b(hi.w);
  return r;
}

// ---- GroupNorm one-pass: stage fp32 tile in LDS (128KB), x read ONCE ----
__global__ __launch_bounds__(512) void gn_kernel(
    const float* __restrict__ x, const float* __restrict__ w,
    const float* __restrict__ bias, unsigned short* __restrict__ xn) {
  int b = blockIdx.x >> 5;
  int g = blockIdx.x & 31;
  const float* xp = x + ((size_t)b * NC + (size_t)g * CPG) * NSP;
  int t = threadIdx.x;

  __shared__ float xs[CPG * NSP];   // 128 KB
  __shared__ float r1[512], r2[512];

  float s = 0.f, ss = 0.f;
  for (int i = 4 * t; i < CPG * NSP; i += 2048) {
    float4 v = *(const float4*)(xp + i);
    *(float4*)(xs + i) = v;
    s += v.x + v.y + v.z + v.w;
    ss += v.x * v.x + v.y * v.y + v.z * v.z + v.w * v.w;
  }
  r1[t] = s; r2[t] = ss;
  __syncthreads();
  for (int off = 256; off > 0; off >>= 1) {
    if (t < off) { r1[t] += r1[t + off]; r2[t] += r2[t + off]; }
    __syncthreads();
  }
  float mean = r1[0] * (1.f / (CPG * NSP));
  float var  = r2[0] * (1.f / (CPG * NSP)) - mean * mean;
  float rstd = rsqrtf(var + GEPS);
  float wv[CPG], bv[CPG];
  for (int c = 0; c < CPG; c++) {
    wv[c] = w[g * CPG + c] * rstd;
    bv[c] = bias[g * CPG + c] - mean * wv[c];
  }
  for (int n = t; n < NSP; n += 512) {
    s8v pk;
    for (int c = 0; c < CPG; c++) {
      float v = xs[c * NSP + n];
      ((unsigned short*)&pk)[c] = f2b(v * wv[c] + bv[c]);
    }
    *(s8v*)(xn + ((size_t)(b * NSP + n) * NC + g * CPG)) = pk;
  }
}

// ---- Fused QKV GEMM, fp32 W inline convert, VECTORIZED epilogues ----
// grid (NSP/128, 6, NB). sec = y>>1 (0=q,1=k,2=v).
// Layouts consumed by flash (unchanged):
//  Q/K: elem (tok,d) at (d>>4)*512 + ((d>>3)&1)*256 + (tok&31)*8 + (d&7)  per 32-tok tile
//  V:   elem (tok,d) at (d>>5)*1024 + ((tok>>3)&3)*256 + (d&31)*8 + (tok&7) per 32-tok tile
__global__ __launch_bounds__(256) void qkv_gemm(
    const float* __restrict__ Wf, const unsigned short* __restrict__ xnG,
    const float* __restrict__ qkvb,
    unsigned short* __restrict__ q, unsigned short* __restrict__ k,
    unsigned short* __restrict__ v) {
  const int sec = blockIdx.y >> 1;
  const int m0 = (blockIdx.y & 1) * 128;
  const int n0 = blockIdx.x * 128;
  const float* A = Wf + (size_t)sec * NC * NC;
  const unsigned short* Bt = xnG + (size_t)blockIdx.z * NSP * NC;
  unsigned short* dst = (sec == 0 ? q : (sec == 1 ? k : v)) + (size_t)blockIdx.z * NSP * NC;
  const float scl = (sec == 0) ? SCALE : 1.f;

  __shared__ unsigned short S[8192];   // As | Bs; reused as V-stage (16 KB)
  unsigned short* As = S;
  unsigned short* Bs = S + 4096;
  const int t = threadIdx.x;
  const int lane = t & 63, wave = t >> 6;
  const int wm = (wave >> 1) * 64, wn = (wave & 1) * 64;
  const int l16 = lane & 15, quad = lane >> 4;
  const int srow = t >> 2, skc = (t & 3) * 8;

  f4v acc[4][4];
  for (int mi = 0; mi < 4; mi++)
    for (int ni = 0; ni < 4; ni++)
      acc[mi][ni] = (f4v){0.f, 0.f, 0.f, 0.f};

  const float* Ag0 = A + (size_t)(m0 + srow) * NC + skc;
  const float* Ag1 = A + (size_t)(m0 + srow + 64) * NC + skc;
  const unsigned short* Bg0 = Bt + (size_t)(n0 + srow) * NC + skc;
  const unsigned short* Bg1 = Bt + (size_t)(n0 + srow + 64) * NC + skc;

  for (int k0 = 0; k0 < NC; k0 += 32) {
    s8v a0 = pack8(*(const float4*)(Ag0 + k0), *(const float4*)(Ag0 + k0 + 4));
    s8v a1 = pack8(*(const float4*)(Ag1 + k0), *(const float4*)(Ag1 + k0 + 4));
    s8v b0 = *(const s8v*)(Bg0 + k0);
    s8v b1 = *(const s8v*)(Bg1 + k0);
    __syncthreads();
    *(s8v*)(As + srow * 32 + skc) = a0;
    *(s8v*)(As + (srow + 64) * 32 + skc) = a1;
    *(s8v*)(Bs + srow * 32 + skc) = b0;
    *(s8v*)(Bs + (srow + 64) * 32 + skc) = b1;
    __syncthreads();
    s8v af[4], bfr[4];
    for (int mi = 0; mi < 4; mi++)
      af[mi] = *(const s8v*)(As + (wm + mi * 16 + l16) * 32 + quad * 8);
    for (int ni = 0; ni < 4; ni++)
      bfr[ni] = *(const s8v*)(Bs + (wn + ni * 16 + l16) * 32 + quad * 8);
    for (int mi = 0; mi < 4; mi++)
      for (int ni = 0; ni < 4; ni++)
        acc[mi][ni] = __builtin_amdgcn_mfma_f32_16x16x32_bf16(af[mi], bfr[ni], acc[mi][ni], 0, 0, 0);
  }

  if (sec < 2) {
    // Q/K: quad-pair shfl merge -> 16B stores from even quads.
    // Even quad holds d rb..rb+3 (rb&7==0), partner quad^1 holds rb+4..rb+7.
    for (int mi = 0; mi < 4; mi++) {
      const int rb = m0 + wm + mi * 16 + quad * 4;
      for (int ni = 0; ni < 4; ni++) {
        const int col = n0 + wn + ni * 16 + l16;
        f4v a = acc[mi][ni];
        unsigned short pk[4];
        for (int r = 0; r < 4; r++)
          pk[r] = f2b((a[r] + qkvb[sec * NC + rb + r]) * scl);
        unsigned w0 = (unsigned)pk[0] | ((unsigned)pk[1] << 16);
        unsigned w1 = (unsigned)pk[2] | ((unsigned)pk[3] << 16);
        unsigned p0 = __shfl_xor(w0, 16, 64);
        unsigned p1 = __shfl_xor(w1, 16, 64);
        if (!(quad & 1)) {
          u4v full; full[0] = w0; full[1] = w1; full[2] = p0; full[3] = p1;
          const size_t off = (size_t)(col >> 5) * 8192 + (rb >> 4) * 512 +
                             ((rb >> 3) & 1) * 256 + (col & 31) * 8;
          *(s8v*)(dst + off) = __builtin_bit_cast(s8v, full);
        }
      }
    }
  } else {
    // V: LDS-stage in destination layout (two 16KB passes), dense 16B copy-out.
    for (int h = 0; h < 2; h++) {
      __syncthreads();
      for (int mi = 0; mi < 4; mi++) {
        const int dlb = wm + mi * 16 + quad * 4;   // local d base 0..127
        for (int nn = 0; nn < 2; nn++) {
          const int ni = 2 * h + nn;
          const int jl = wn + ni * 16 + l16;       // local token 0..127
          f4v a = acc[mi][ni];
          const int base = ((jl >> 6) & 1) * 4096 + ((jl >> 3) & 3) * 256 + (jl & 7);
          for (int r = 0; r < 4; r++) {
            const int dl = dlb + r;
            S[base + (dl >> 5) * 1024 + (dl & 31) * 8] =
                f2b(a[r] + qkvb[2 * NC + m0 + dl]);
          }
        }
      }
      __syncthreads();
      // copy out 8192 shorts: chunk c = 8 shorts; lanes contiguous -> 1KB/wave-instr
      for (int i = 0; i < 4; i++) {
        const int c = i * 256 + t;
        const int jtbit = c >> 9;
        const int dgrp = (c >> 7) & 3;
        const int rest = (c & 127) * 8;
        unsigned short* gdst = dst + (size_t)(n0 / 32 + 2 * jtbit + h) * 8192 +
                               (size_t)(m0 / 32 + dgrp) * 1024 + rest;
        *(s8v*)gdst = *(const s8v*)(S + c * 8);
      }
    }
  }
}

// ---- Flash v12 == v11 main loop (best: 76.3us), epilogue 16B-merged stores ----
__global__ __launch_bounds__(256, 2) void flash12_kernel(
    const unsigned short* __restrict__ q, const unsigned short* __restrict__ k,
    const unsigned short* __restrict__ v, unsigned short* __restrict__ Opart,
    float* __restrict__ Lpart) {
  const int qt = blockIdx.x, b = blockIdx.y, js = blockIdx.z;
  const size_t sNC = (size_t)NSP * NC;
  const unsigned short* qb = q + b * sNC;
  const unsigned short* kb = k + b * sNC;
  const unsigned short* vb = v + b * sNC;
  const int t = threadIdx.x, lane = t & 63, w = t >> 6;

  __shared__ unsigned short K_lds[2][16 * 512];  // 32 j x 256 d, frag-linear
  __shared__ unsigned short V_lds[2][16 * 512];  // 32 j x 256 d, V^T frag-linear

  f16v zero16;
  #pragma unroll
  for (int r = 0; r < 16; r++) zero16[r] = 0.f;

  // Q resident as B-frags: wave w owns 32-token tile qt*4 + w
  s8v qf[16];
  {
    const unsigned short* qp = qb + (size_t)(qt * 4 + w) * 8192 + lane * 8;
    #pragma unroll
    for (int kc = 0; kc < 16; kc++)
      qf[kc] = *(const s8v*)(qp + kc * 512);
  }

  f16v accO[8];
  #pragma unroll
  for (int dt = 0; dt < 8; dt++) accO[dt] = zero16;
  float l4[4] = {0.f, 0.f, 0.f, 0.f};

  const int jbeg = js * (NSP / JSPLIT);
  const int NT = (NSP / JSPLIT) / 32;

  auto stage = [&](int j0, int bufsel) {
    const size_t tb = (size_t)(j0 >> 5) * 16;
    #pragma unroll
    for (int ii = 0; ii < 8; ii++) {
      const int idx = w * 8 + ii;  // waves 0-1: K chunks 0..15; waves 2-3: V chunks
      const unsigned short* gp;
      unsigned short* ld;
      if (idx < 16) {
        gp = kb + (tb + idx) * 512 + lane * 8;
        ld = &K_lds[bufsel][idx * 512];
      } else {
        const int dt = idx - 16;
        gp = vb + (tb + dt) * 512 + lane * 8;
        ld = &V_lds[bufsel][dt * 512];
      }
      __builtin_amdgcn_global_load_lds(
          (const __attribute__((address_space(1))) unsigned int*)gp,
          (__attribute__((address_space(3))) unsigned int*)ld, 16, 0, 0);
    }
  };

  stage(jbeg, 0);
  for (int jt = 0; jt < NT; jt++) {
    __syncthreads();
    if (jt + 1 < NT) stage(jbeg + (jt + 1) * 32, (jt + 1) & 1);
    const unsigned short* Kc = K_lds[jt & 1];
    const unsigned short* Vc = V_lds[jt & 1];

    // S^T = K . Q^T over d = 256 (16 k-steps)
    f16v accS = zero16;
    #pragma unroll
    for (int kc = 0; kc < 16; kc++) {
      s8v kf = *(const s8v*)(Kc + kc * 512 + lane * 8);
      accS = __builtin_amdgcn_mfma_f32_32x32x16_bf16(kf, qf[kc], accS, 0, 0, 0);
    }

    // p = exp(s): q pre-scaled, no max (80-sigma headroom); l lane-local (col=q)
    float p[16];
    #pragma unroll
    for (int r = 0; r < 16; r++) {
      p[r] = __expf(accS[r]);
      l4[r & 3] += p[r];
    }

    // Repack P rows (j) into PV B-frags (T12: packbf + permlane32_swap)
    u4v pw0, pw1;
    {
      unsigned a0 = packbf(p[0], p[1]),   b0 = packbf(p[4], p[5]);
      asm("v_permlane32_swap_b32 %0, %1" : "+v"(a0), "+v"(b0));
      unsigned a1 = packbf(p[2], p[3]),   b1 = packbf(p[6], p[7]);
      asm("v_permlane32_swap_b32 %0, %1" : "+v"(a1), "+v"(b1));
      unsigned a2 = packbf(p[8], p[9]),   b2 = packbf(p[12], p[13]);
      asm("v_permlane32_swap_b32 %0, %1" : "+v"(a2), "+v"(b2));
      unsigned a3 = packbf(p[10], p[11]), b3 = packbf(p[14], p[15]);
      asm("v_permlane32_swap_b32 %0, %1" : "+v"(a3), "+v"(b3));
      pw0[0] = a0; pw0[1] = a1; pw0[2] = b0; pw0[3] = b1;  // j-half 0 (j=0..15)
      pw1[0] = a2; pw1[1] = a3; pw1[2] = b2; pw1[3] = b3;  // j-half 1 (j=16..31)
    }
    const s8v pb0 = __builtin_bit_cast(s8v, pw0);
    const s8v pb1 = __builtin_bit_cast(s8v, pw1);

    // out^T += V^T . P^T : 8 d-tiles x 2 j-halves
    #pragma unroll
    for (int dt = 0; dt < 8; dt++) {
      s8v vf0 = *(const s8v*)(Vc + dt * 1024 + lane * 8);
      s8v vf1 = *(const s8v*)(Vc + dt * 1024 + 512 + lane * 8);
      accO[dt] = __builtin_amdgcn_mfma_f32_32x32x16_bf16(vf0, pb0, accO[dt], 0, 0, 0);
      accO[dt] = __builtin_amdgcn_mfma_f32_32x32x16_bf16(vf1, pb1, accO[dt], 0, 0, 0);
    }
  }

  // epilogue: lane owns q = lane&31; hi-halves (lane, lane+32) share qrow ->
  // shfl_xor(32) merge gives full 16B chunks, stored by hi==0 lanes.
  float l_acc = l4[0] + l4[1] + l4[2] + l4[3];
  const float ltot = l_acc + __shfl_xor(l_acc, 32, 64);
  const int qrow = b * NSP + qt * 128 + w * 32 + (lane & 31);
  if (lane < 32)
    Lpart[(size_t)js * NROWS + qrow] = ltot;

  unsigned short* Op = Opart + ((size_t)js * NROWS + qrow) * NC;
  const int hi = lane >> 5;
  #pragma unroll
  for (int dt = 0; dt < 8; dt++) {
    #pragma unroll
    for (int g = 0; g < 4; g++) {
      unsigned short pk[4];
      #pragma unroll
      for (int r = 0; r < 4; r++)
        pk[r] = f2b(accO[dt][g * 4 + r]);
      unsigned w0 = (unsigned)pk[0] | ((unsigned)pk[1] << 16);
      unsigned w1 = (unsigned)pk[2] | ((unsigned)pk[3] << 16);
      unsigned p0 = __shfl_xor(w0, 32, 64);
      unsigned p1 = __shfl_xor(w1, 32, 64);
      if (hi == 0) {
        u4v full; full[0] = w0; full[1] = w1; full[2] = p0; full[3] = p1;
        // d = dt*32 + g*8 + {0..7}
        *(s8v*)(Op + dt * 32 + g * 8) = __builtin_bit_cast(s8v, full);
      }
    }
  }
}

// ---- Fused proj GEMM: fp32 W inline-converted + inline merge of JSPLIT partials ----
__global__ __launch_bounds__(256) void proj_gemm(
    const float* __restrict__ Wpf, const unsigned short* __restrict__ Opart,
    const float* __restrict__ Lpart, const float* __restrict__ pb,
    const float* __restrict__ x, float* __restrict__ out) {
  const int z = blockIdx.z, m0 = blockIdx.y * 128, n0 = blockIdx.x * 128;
  __shared__ unsigned short As[128 * 32], Bs[128 * 32];
  const int t = threadIdx.x;
  const int lane = t & 63, wave = t >> 6;
  const int wm = (wave >> 1) * 64, wn = (wave & 1) * 64;
  const int l16 = lane & 15, quad = lane >> 4;
  const int srow = t >> 2, skc = (t & 3) * 8;

  const int prow0 = z * NSP + n0 + srow;
  const int prow1 = prow0 + 64;
  float ls0 = 0.f, ls1 = 0.f;
  for (int js = 0; js < JSPLIT; js++) {
    ls0 += Lpart[(size_t)js * NROWS + prow0];
    ls1 += Lpart[(size_t)js * NROWS + prow1];
  }
  const float inv0 = 1.f / ls0, inv1 = 1.f / ls1;

  f4v acc[4][4];
  for (int mi = 0; mi < 4; mi++)
    for (int ni = 0; ni < 4; ni++)
      acc[mi][ni] = (f4v){0.f, 0.f, 0.f, 0.f};

  const float* Ag0 = Wpf + (size_t)(m0 + srow) * NC + skc;
  const float* Ag1 = Wpf + (size_t)(m0 + srow + 64) * NC + skc;

  for (int k0 = 0; k0 < NC; k0 += 32) {
    s8v a0 = pack8(*(const float4*)(Ag0 + k0), *(const float4*)(Ag0 + k0 + 4));
    s8v a1 = pack8(*(const float4*)(Ag1 + k0), *(const float4*)(Ag1 + k0 + 4));
    float bv0[8], bv1[8];
    for (int e = 0; e < 8; e++) { bv0[e] = 0.f; bv1[e] = 0.f; }
    for (int js = 0; js < JSPLIT; js++) {
      const s8v o0 = *(const s8v*)(Opart + ((size_t)js * NROWS + prow0) * NC + k0 + skc);
      const s8v o1 = *(const s8v*)(Opart + ((size_t)js * NROWS + prow1) * NC + k0 + skc);
      for (int e = 0; e < 8; e++) {
        bv0[e] += b2f(((const unsigned short*)&o0)[e]);
        bv1[e] += b2f(((const unsigned short*)&o1)[e]);
      }
    }
    s8v b0, b1;
    for (int e = 0; e < 8; e++) {
      ((unsigned short*)&b0)[e] = f2b(bv0[e] * inv0);
      ((unsigned short*)&b1)[e] = f2b(bv1[e] * inv1);
    }
    __syncthreads();
    *(s8v*)(As + srow * 32 + skc) = a0;
    *(s8v*)(As + (srow + 64) * 32 + skc) = a1;
    *(s8v*)(Bs + srow * 32 + skc) = b0;
    *(s8v*)(Bs + (srow + 64) * 32 + skc) = b1;
    __syncthreads();
    s8v af[4], bfr[4];
    for (int mi = 0; mi < 4; mi++)
      af[mi] = *(const s8v*)(As + (wm + mi * 16 + l16) * 32 + quad * 8);
    for (int ni = 0; ni < 4; ni++)
      bfr[ni] = *(const s8v*)(Bs + (wn + ni * 16 + l16) * 32 + quad * 8);
    for (int mi = 0; mi < 4; mi++)
      for (int ni = 0; ni < 4; ni++)
        acc[mi][ni] = __builtin_amdgcn_mfma_f32_16x16x32_bf16(af[mi], bfr[ni], acc[mi][ni], 0, 0, 0);
  }

  float* C = out + (size_t)z * NC * NSP;
  const float* R = x + (size_t)z * NC * NSP;
  for (int mi = 0; mi < 4; mi++) {
    const int rb = m0 + wm + mi * 16 + quad * 4;
    for (int ni = 0; ni < 4; ni++) {
      const int col = n0 + wn + ni * 16 + l16;
      f4v a = acc[mi][ni];
      for (int r = 0; r < 4; r++)
        C[(size_t)(rb + r) * NSP + col] =
            a[r] + pb[rb + r] + R[(size_t)(rb + r) * NSP + col];
    }
  }
}

extern "C" void kernel_launch(void* const* d_in, const int* in_sizes, int n_in,
                              void* d_out, int out_size, void* d_ws, size_t ws_size,
                              hipStream_t stream) {
  const float* x      = (const float*)d_in[0];
  const float* norm_w = (const float*)d_in[1];
  const float* norm_b = (const float*)d_in[2];
  const float* qkv_w  = (const float*)d_in[3];
  const float* qkv_b  = (const float*)d_in[4];
  const float* proj_w = (const float*)d_in[5];
  const float* proj_b = (const float*)d_in[6];
  float* out = (float*)d_out;  // fp32 output

  char* ws = (char*)d_ws;
  char* wst = ws + (1 << 20);
  const size_t szBNC = (size_t)NB * NSP * NC * 2;  // 8.4 MB (bf16)
  unsigned short* xn = (unsigned short*)wst;
  unsigned short* q  = (unsigned short*)(wst + szBNC);    // frag-tiled, pre-scaled
  unsigned short* k  = (unsigned short*)(wst + 2 * szBNC);// frag-tiled
  unsigned short* v  = (unsigned short*)(wst + 3 * szBNC);// V^T frag-tiled
  unsigned short* Opart = (unsigned short*)(wst + 4 * szBNC);  // 33.6 MB
  float* Lpart = (float*)(wst + 4 * szBNC + (size_t)JSPLIT * NROWS * NC * 2);  // 256 KB
  // peak ws: 68.4 MB (proven-safe <= 76.6 MB)

  gn_kernel<<<dim3(NB * NG), 512, 0, stream>>>(x, norm_w, norm_b, xn);
  qkv_gemm<<<dim3(NSP / 128, 6, NB), 256, 0, stream>>>(qkv_w, xn, qkv_b, q, k, v);
  flash12_kernel<<<dim3(NSP / 128, NB, JSPLIT), 256, 0, stream>>>(q, k, v, Opart, Lpart);
  proj_gemm<<<dim3(NSP / 128, NC / 128, NB), 256, 0, stream>>>(
      proj_w, Opart, Lpart, proj_b, x, out);
}